// Round 5
// baseline (334.838 us; speedup 1.0000x reference)
//
#include <hip/hip_runtime.h>
#include <stdint.h>

typedef short bf16x8 __attribute__((ext_vector_type(8)));
typedef float f32x16 __attribute__((ext_vector_type(16)));

#define LN2f  0.69314718055994530942f

constexpr int Bn = 512;
constexpr int Ln = 2048;
constexpr int Cn = 32;
constexpr int NSEG = 64;      // 1024 scan units
constexpr int SEGLEN = 32;    // Ln / NSEG
constexpr int WARM = 16;
constexpr int NGRP = 16;      // Bn / 32
constexpr int WPB  = 4;       // waves per block
constexpr int NSLOT = 4;      // LDS tile ring per wave (4 x 4KB)

// pack two f32 -> one VGPR of two bf16 (round-half-away via +0x8000, then take high halves)
__device__ __forceinline__ uint32_t pack2_bf16(float lo, float hi) {
    uint32_t a = __float_as_uint(lo) + 0x8000u;
    uint32_t b = __float_as_uint(hi) + 0x8000u;
    return __builtin_amdgcn_perm(b, a, 0x07060302u);
}

// crf_scan v5: NO global_load_lds, NO inline-asm waits.
// Rounds 0-4 evidence: per-CU step rate pinned ~1/1200cy regardless of occupancy,
// placement, memory source, request pattern, chain length. r4 (stricter manual
// vmcnt) REGRESSED with VALUBusy dropping 18->9%: the controlling term is VMEM
// waits. With global_load_lds the compiler can't disprove DMA/ds_read aliasing
// and inserts its own vmcnt(0) drain before the LDS reads every step -> each
// step exposes the latency of loads issued ~1 step earlier.
// v5 stages through registers: global_load_dwordx4 (coalesced, issued 6 steps
// ahead into a 4-buffer VGPR ring) -> ds_write_b128 (XOR-swizzled write side)
// -> ds_read_b128 fragment. All deps register-tracked => compiler emits counted
// vmcnt/lgkmcnt; nothing drains the pipeline.
// exp stays one step off-chain: step i consumes Eg=exp(e_i) computed at step i-1.
__global__ __launch_bounds__(256, 1) void crf_scan(
    const float* __restrict__ emis, const float* __restrict__ trans,
    float* __restrict__ dDelta)
{
    __shared__ float ELDS[WPB][NSLOT][1024];   // 64 KiB
    const int lane = threadIdx.x & 63;
    const int wid  = threadIdx.x >> 6;
    const int h    = lane >> 5;
    const int bl   = lane & 31;
    const int bl7  = bl & 7;
    const int lr   = lane >> 3;   // 0..7  (row-in-octet for staging)
    const int lc   = lane & 7;    // 0..7  (16B chunk for staging)
    const int unit = blockIdx.x * WPB + wid;   // 0..1023
    const int g    = unit & (NGRP - 1);
    const int s    = unit >> 4;                // 0..NSEG-1
    const int b    = g * 32 + bl;

    // global element offsets per staging instr q: batch row g*32+8q+lr, chunk lc
    uint32_t goff[4];
    #pragma unroll
    for (int q = 0; q < 4; ++q)
        goff[q] = (uint32_t)((g * 32 + 8 * q + lr) * (Ln * Cn) + lc * 4);

    // Constant A fragments: A[m=bl][k'], k' = 8h + j; col(j) = 4h + (j&3) + 8*(j>>2) (+16 for A2)
    bf16x8 A1, A2;
    {
        float e1[8], e2[8];
        #pragma unroll
        for (int j = 0; j < 8; ++j) {
            int c1 = 4 * h + (j & 3) + 8 * (j >> 2);
            e1[j] = __expf(trans[bl * Cn + c1]);
            e2[j] = __expf(trans[bl * Cn + c1 + 16]);
        }
        union { uint32_t u[4]; bf16x8 v; } ua, ub;
        #pragma unroll
        for (int q = 0; q < 4; ++q) {
            ua.u[q] = pack2_bf16(e1[2*q], e1[2*q+1]);
            ub.u[q] = pack2_bf16(e2[2*q], e2[2*q+1]);
        }
        A1 = ua.v; A2 = ub.v;
    }

    const f32x16 zeroC = {0.f,0.f,0.f,0.f,0.f,0.f,0.f,0.f,0.f,0.f,0.f,0.f,0.f,0.f,0.f,0.f};

    f32x16 Dv;
    bf16x8 B1, B2;
    float  Eg[16];             // exp(e_i), produced at step i-1
    float4 Rg[4][4];           // 4-deep register tile ring (64 VGPRs)
    float  offF = 0.f;

    const int t0 = (s == 0) ? 0 : s * SEGLEN - WARM;
    const int NT = (s == 0) ? SEGLEN : (SEGLEN + WARM);

    auto gload = [&](int t, float4 (&dst)[4]) {
        #pragma unroll
        for (int q = 0; q < 4; ++q)
            dst[q] = *(const float4*)(emis + (size_t)goff[q] + (size_t)t * Cn);
    };

    // write-side XOR swizzle: chunk lc of row 8q+lr stored at chunk lc^lr
    auto dswrite = [&](int slot, const float4 (&src)[4]) {
        #pragma unroll
        for (int q = 0; q < 4; ++q)
            *(float4*)&ELDS[wid][slot][(8 * q + lr) * 32 + (lc ^ lr) * 4] = src[q];
    };

    // fragment read: lane(bl,h), q -> global chunk (h+2q) of row bl, at (h+2q)^(bl&7)
    auto readFrag = [&](int slot, float4 (&bu)[4]) {
        #pragma unroll
        for (int q = 0; q < 4; ++q)
            bu[q] = *(const float4*)&ELDS[wid][slot][bl * 32 + ((h + 2 * q) ^ bl7) * 4];
    };

    auto packB = [&]() {
        union { uint32_t u[4]; bf16x8 v; } p1, p2;
        #pragma unroll
        for (int q = 0; q < 4; ++q) {
            p1.u[q] = pack2_bf16(Dv[2*q],     Dv[2*q + 1]);
            p2.u[q] = pack2_bf16(Dv[8 + 2*q], Dv[8 + 2*q + 1]);
        }
        B1 = p1.v; B2 = p2.v;
    };

    auto sumD = [&]() {
        float t = 0.f;
        #pragma unroll
        for (int r = 0; r < 16; ++r) t += Dv[r];
        t += __shfl_xor(t, 32, 64);
        return t;
    };

    // step i (u = i&7, static under unroll; base of each 8-block is %4==0 so all
    // ring indices depend only on u). mode: 0 none, 1 pow2-renorm, 2 boundary.
    // Body: read frag(i+1) | MFMA+mul by Eg(e_i) | pack | Eg=exp(frag) |
    //       ds_write tile i+3 (loaded 3 steps ago) | issue load tile i+6.
    auto step = [&](int u, int i, bool isInit, int mode) {
        float4 bu[4];
        readFrag((u + 1) & 3, bu);             // raw e_{i+1}
        if (isInit) {
            #pragma unroll
            for (int r = 0; r < 16; ++r) Dv[r] = Eg[r];
        } else {
            f32x16 acc = __builtin_amdgcn_mfma_f32_32x32x16_bf16(A1, B1, zeroC, 0, 0, 0);
            acc = __builtin_amdgcn_mfma_f32_32x32x16_bf16(A2, B2, acc, 0, 0, 0);
            #pragma unroll
            for (int r = 0; r < 16; ++r) Dv[r] = acc[r] * Eg[r];
        }
        if (mode == 1) {
            float m0 = fmaxf(fmaxf(Dv[0], Dv[1]),  fmaxf(Dv[2],  Dv[3]));
            float m1 = fmaxf(fmaxf(Dv[4], Dv[5]),  fmaxf(Dv[6],  Dv[7]));
            float m2 = fmaxf(fmaxf(Dv[8], Dv[9]),  fmaxf(Dv[10], Dv[11]));
            float m3 = fmaxf(fmaxf(Dv[12],Dv[13]), fmaxf(Dv[14], Dv[15]));
            float m  = fmaxf(fmaxf(m0, m1), fmaxf(m2, m3));
            m = fmaxf(m, __shfl_xor(m, 32, 64));
            int k = (int)((__float_as_uint(m) >> 23) & 0xffu) - 126;
            offF += (float)k * LN2f;
            float sc = __uint_as_float((uint32_t)(127 - k) << 23);   // exact 2^-k
            #pragma unroll
            for (int r = 0; r < 16; ++r) Dv[r] *= sc;
        } else if (mode == 2) {
            float S = sumD();
            float inv = 1.0f / S;
            offF = 0.f;
            #pragma unroll
            for (int r = 0; r < 16; ++r) Dv[r] *= inv;
        }
        packB();
        #pragma unroll
        for (int q = 0; q < 4; ++q) {          // off-chain: Eg = exp(e_{i+1})
            Eg[4*q+0] = __expf(bu[q].x);
            Eg[4*q+1] = __expf(bu[q].y);
            Eg[4*q+2] = __expf(bu[q].z);
            Eg[4*q+3] = __expf(bu[q].w);
        }
        dswrite((u + 3) & 3, Rg[(u + 3) & 3]); // tile i+3 -> LDS (loaded at step i-3)
        int tt = t0 + min(i + 6, NT - 1);
        gload(tt, Rg[(u + 6) & 3]);            // issue tile i+6
    };

    // ---- prologue: tiles 0,1,2 -> LDS slots 0,1,2; tiles 3,4,5 in reg ring
    gload(t0 + 0, Rg[0]);
    gload(t0 + 1, Rg[1]);
    gload(t0 + 2, Rg[2]);
    dswrite(0, Rg[0]);
    dswrite(1, Rg[1]);
    dswrite(2, Rg[2]);
    gload(t0 + 3, Rg[3]);
    gload(t0 + 4, Rg[0]);
    gload(t0 + 5, Rg[1]);
    {
        float4 b0[4];
        readFrag(0, b0);                       // e_{t0}
        #pragma unroll
        for (int q = 0; q < 4; ++q) {
            Eg[4*q+0] = __expf(b0[q].x);  Eg[4*q+1] = __expf(b0[q].y);
            Eg[4*q+2] = __expf(b0[q].z);  Eg[4*q+3] = __expf(b0[q].w);
        }
    }

    if (s == 0) {
        // i = 0..31; init at 0; renorm at 7,15,23
        step(0, 0, true, 0);
        #pragma unroll
        for (int u = 1; u < 8; ++u) step(u, u, false, (u == 7) ? 1 : 0);
        #pragma unroll 1
        for (int blk = 1; blk < 4; ++blk) {
            const int base = blk * 8;
            #pragma unroll
            for (int u = 0; u < 8; ++u)
                step(u, base + u, false, (u == 7 && blk < 3) ? 1 : 0);
        }
    } else {
        // i = 0..47; init at 0; renorm at 7; boundary sum-normalize at 15
        // (t = s*SEGLEN - 1); renorm at 23,31,39
        step(0, 0, true, 0);
        #pragma unroll
        for (int u = 1; u < 8; ++u) step(u, u, false, (u == 7) ? 1 : 0);
        #pragma unroll
        for (int u = 0; u < 8; ++u) step(u, 8 + u, false, (u == 7) ? 2 : 0);
        #pragma unroll 1
        for (int blk = 2; blk < 6; ++blk) {
            const int base = blk * 8;
            #pragma unroll
            for (int u = 0; u < 8; ++u)
                step(u, base + u, false, (u == 7 && blk < 5) ? 1 : 0);
        }
    }

    float Sf = sumD();
    float delta = offF + __logf(Sf);
    if (lane < 32) {
        dDelta[s * Bn + b] = delta;
    }
}

// Per-batch gold-path score + msum + last-emission + per-batch total (logZ - score).
__global__ __launch_bounds__(256) void crf_score(
    const float* __restrict__ emis, const float* __restrict__ trans,
    const int* __restrict__ tags, const int* __restrict__ mask,
    const float* __restrict__ dDelta, float* __restrict__ dVal)
{
    __shared__ float Tl[Cn * Cn];
    __shared__ float redS[4];
    __shared__ int   redM[4];
    const int b = blockIdx.x;
    const int tid = threadIdx.x;
    for (int i = tid; i < Cn * Cn; i += 256) Tl[i] = trans[i];
    __syncthreads();

    const size_t tB = (size_t)b * Ln;
    const size_t eb = (size_t)b * Ln * Cn;
    const int t0 = tid * 8;

    int tg[9], mk[9];
    {
        int4 a0 = *(const int4*)(tags + tB + t0);
        int4 a1 = *(const int4*)(tags + tB + t0 + 4);
        int4 c0 = *(const int4*)(mask + tB + t0);
        int4 c1 = *(const int4*)(mask + tB + t0 + 4);
        tg[0]=a0.x; tg[1]=a0.y; tg[2]=a0.z; tg[3]=a0.w;
        tg[4]=a1.x; tg[5]=a1.y; tg[6]=a1.z; tg[7]=a1.w;
        mk[0]=c0.x; mk[1]=c0.y; mk[2]=c0.z; mk[3]=c0.w;
        mk[4]=c1.x; mk[5]=c1.y; mk[6]=c1.z; mk[7]=c1.w;
        tg[8] = (t0 + 8 < Ln) ? tags[tB + t0 + 8] : 0;
        mk[8] = (t0 + 8 < Ln) ? mask[tB + t0 + 8] : 0;
    }

    float sc = 0.f; int ms = 0;
    #pragma unroll
    for (int u = 0; u < 8; ++u) {
        int t = t0 + u;
        ms += mk[u];
        if (t < Ln - 1) {
            sc += (float)mk[u]     * emis[eb + (size_t)t * Cn + tg[u]];
            sc += (float)mk[u + 1] * Tl[(tg[u] << 5) + tg[u + 1]];
        }
    }
    #pragma unroll
    for (int o = 32; o > 0; o >>= 1) {
        sc += __shfl_down(sc, o, 64);
        ms += __shfl_down(ms, o, 64);
    }
    if ((tid & 63) == 0) { redS[tid >> 6] = sc; redM[tid >> 6] = ms; }
    __syncthreads();

    if (tid < NSEG) {
        float lz = dDelta[(size_t)tid * Bn + b];
        #pragma unroll
        for (int o = 32; o > 0; o >>= 1) lz += __shfl_down(lz, o, 64);
        if (tid == 0) {
            float scT = redS[0] + redS[1] + redS[2] + redS[3];
            int   msT = redM[0] + redM[1] + redM[2] + redM[3];
            int last_idx = max(msT - 1, 0);
            int le_t     = max(msT, 1) - 1;
            int lt = tags[tB + last_idx];
            float le = emis[eb + (size_t)le_t * Cn + lt];
            dVal[b] = lz - (scT + le);
        }
    }
}

__global__ void crf_final(const float* __restrict__ dVal, float* __restrict__ out)
{
    __shared__ float red[8];
    int b = threadIdx.x;   // 512 threads = one per batch
    float val = dVal[b];
    #pragma unroll
    for (int o = 32; o > 0; o >>= 1) val += __shfl_down(val, o, 64);
    if ((b & 63) == 0) red[b >> 6] = val;
    __syncthreads();
    if (b == 0) {
        float t = 0.f;
        #pragma unroll
        for (int w = 0; w < 8; ++w) t += red[w];
        out[0] = t * (1.0f / (float)Bn);
    }
}

extern "C" void kernel_launch(void* const* d_in, const int* in_sizes, int n_in,
                              void* d_out, int out_size, void* d_ws, size_t ws_size,
                              hipStream_t stream)
{
    const float* emis  = (const float*)d_in[0];
    const float* trans = (const float*)d_in[1];
    const int*   tags  = (const int*)d_in[2];
    const int*   mask  = (const int*)d_in[3];
    float* wsf = (float*)d_ws;
    float* dDelta = wsf;                 // NSEG*Bn f32
    float* dVal   = wsf + NSEG * Bn;     // Bn f32
    crf_scan<<<(NGRP * NSEG) / WPB, 64 * WPB, 0, stream>>>(emis, trans, dDelta);
    crf_score<<<Bn, 256, 0, stream>>>(emis, trans, tags, mask, dDelta, dVal);
    crf_final<<<1, Bn, 0, stream>>>(dVal, (float*)d_out);
}

// Round 6
// 254.681 us; speedup vs baseline: 1.3147x; 1.3147x over previous
//
#include <hip/hip_runtime.h>
#include <stdint.h>

typedef short bf16x8 __attribute__((ext_vector_type(8)));
typedef float f32x16 __attribute__((ext_vector_type(16)));

#define LN2f  0.69314718055994530942f

constexpr int Bn = 512;
constexpr int Ln = 2048;
constexpr int Cn = 32;
constexpr int NSEG = 64;      // 1024 scan units
constexpr int SEGLEN = 32;    // Ln / NSEG
constexpr int WARM = 16;
constexpr int NGRP = 16;      // Bn / 32
constexpr int WPB  = 4;       // waves per block
constexpr int NSLOT = 4;      // LDS tile ring per wave (4 x 4KB)

// pack two f32 -> one VGPR of two bf16 (round-half-away via +0x8000, then take high halves)
__device__ __forceinline__ uint32_t pack2_bf16(float lo, float hi) {
    uint32_t a = __float_as_uint(lo) + 0x8000u;
    uint32_t b = __float_as_uint(hi) + 0x8000u;
    return __builtin_amdgcn_perm(b, a, 0x07060302u);
}

// crf_scan v6 = v5's pipeline with the register spill made structurally impossible.
// v5 post-mortem: WRITE_SIZE 128KB -> 182MB and VGPR 92 => the Rg[4][4] ring was
// spilled to scratch (element-selected array-of-arrays through a lambda ref broke
// SROA); every step round-tripped its 4KB tile through HBM scratch.
// v6: TWO NAMED buffers G0/G1 chosen by literal if((u&1)==0) under full unroll.
// Each step: ds_write Gb (tile i+2, loaded 2 steps ago) -> reload Gb (tile i+4).
// Live staging regs capped at 32 by construction. No inline asm anywhere: all
// deps register-tracked => compiler emits counted vmcnt/lgkmcnt, no drains.
// Staging stays coalesced (each load instr = 8 batches x contiguous 16B chunks);
// LDS does the batch<->lane transpose with write-side XOR swizzle.
// exp stays one step off-chain: step i consumes Eg=exp(e_i) computed at step i-1.
__global__ __launch_bounds__(256, 1) void crf_scan(
    const float* __restrict__ emis, const float* __restrict__ trans,
    float* __restrict__ dDelta)
{
    __shared__ float ELDS[WPB][NSLOT][1024];   // 64 KiB
    const int lane = threadIdx.x & 63;
    const int wid  = threadIdx.x >> 6;
    const int h    = lane >> 5;
    const int bl   = lane & 31;
    const int bl7  = bl & 7;
    const int lr   = lane >> 3;   // 0..7  (row-in-octet for staging)
    const int lc   = lane & 7;    // 0..7  (16B chunk for staging)
    const int unit = blockIdx.x * WPB + wid;   // 0..1023
    const int g    = unit & (NGRP - 1);
    const int s    = unit >> 4;                // 0..NSEG-1
    const int b    = g * 32 + bl;

    // per-lane constant offsets (element units)
    uint32_t goff[4];   // global: batch row g*32+8q+lr, chunk lc
    uint32_t wb[4];     // LDS write idx within slot: row 8q+lr, chunk lc^lr
    uint32_t rb[4];     // LDS read idx within slot: row bl, chunk (h+2q)^bl7
    #pragma unroll
    for (int q = 0; q < 4; ++q) {
        goff[q] = (uint32_t)((g * 32 + 8 * q + lr) * (Ln * Cn) + lc * 4);
        wb[q]   = (uint32_t)((8 * q + lr) * 32 + (lc ^ lr) * 4);
        rb[q]   = (uint32_t)(bl * 32 + ((h + 2 * q) ^ bl7) * 4);
    }

    // Constant A fragments: A[m=bl][k'], k' = 8h + j; col(j) = 4h + (j&3) + 8*(j>>2) (+16 for A2)
    bf16x8 A1, A2;
    {
        float e1[8], e2[8];
        #pragma unroll
        for (int j = 0; j < 8; ++j) {
            int c1 = 4 * h + (j & 3) + 8 * (j >> 2);
            e1[j] = __expf(trans[bl * Cn + c1]);
            e2[j] = __expf(trans[bl * Cn + c1 + 16]);
        }
        union { uint32_t u[4]; bf16x8 v; } ua, ub;
        #pragma unroll
        for (int q = 0; q < 4; ++q) {
            ua.u[q] = pack2_bf16(e1[2*q], e1[2*q+1]);
            ub.u[q] = pack2_bf16(e2[2*q], e2[2*q+1]);
        }
        A1 = ua.v; A2 = ub.v;
    }

    const f32x16 zeroC = {0.f,0.f,0.f,0.f,0.f,0.f,0.f,0.f,0.f,0.f,0.f,0.f,0.f,0.f,0.f,0.f};

    f32x16 Dv;
    bf16x8 B1, B2;
    float  Eg[16];             // exp(e_i), produced at step i-1
    float4 G0[4], G1[4];       // NAMED double buffers (32 VGPRs total, capped)
    float  offF = 0.f;

    const int t0 = (s == 0) ? 0 : s * SEGLEN - WARM;
    const int NT = (s == 0) ? SEGLEN : (SEGLEN + WARM);

    auto gload = [&](int t, float4 (&dst)[4]) {
        const float* p = emis + (size_t)t * Cn;
        #pragma unroll
        for (int q = 0; q < 4; ++q)
            dst[q] = *(const float4*)(p + goff[q]);
    };

    auto dswrite = [&](int slot, const float4 (&src)[4]) {
        #pragma unroll
        for (int q = 0; q < 4; ++q)
            *(float4*)&ELDS[wid][slot][wb[q]] = src[q];
    };

    auto readFrag = [&](int slot, float4 (&bu)[4]) {
        #pragma unroll
        for (int q = 0; q < 4; ++q)
            bu[q] = *(const float4*)&ELDS[wid][slot][rb[q]];
    };

    auto packB = [&]() {
        union { uint32_t u[4]; bf16x8 v; } p1, p2;
        #pragma unroll
        for (int q = 0; q < 4; ++q) {
            p1.u[q] = pack2_bf16(Dv[2*q],     Dv[2*q + 1]);
            p2.u[q] = pack2_bf16(Dv[8 + 2*q], Dv[8 + 2*q + 1]);
        }
        B1 = p1.v; B2 = p2.v;
    };

    auto sumD = [&]() {
        float t = 0.f;
        #pragma unroll
        for (int r = 0; r < 16; ++r) t += Dv[r];
        t += __shfl_xor(t, 32, 64);
        return t;
    };

    // step i (u = i&7, literal under unroll). mode: 0 none, 1 pow2-renorm, 2 boundary.
    // Gb: the parity buffer holding tile i+2 (loaded at step i-2).
    // Body: read frag e_{i+1} | MFMA+mul Eg | renorm | pack | Eg=exp(e_{i+1}) |
    //       ds_write tile i+2 from Gb | reload Gb with tile i+4.
    auto step = [&](int u, int i, bool isInit, int mode, float4 (&Gb)[4]) {
        float4 bu[4];
        readFrag((u + 1) & 3, bu);             // raw e_{i+1} (written at step i-1)
        if (isInit) {
            #pragma unroll
            for (int r = 0; r < 16; ++r) Dv[r] = Eg[r];
        } else {
            f32x16 acc = __builtin_amdgcn_mfma_f32_32x32x16_bf16(A1, B1, zeroC, 0, 0, 0);
            acc = __builtin_amdgcn_mfma_f32_32x32x16_bf16(A2, B2, acc, 0, 0, 0);
            #pragma unroll
            for (int r = 0; r < 16; ++r) Dv[r] = acc[r] * Eg[r];
        }
        if (mode == 1) {
            float m0 = fmaxf(fmaxf(Dv[0], Dv[1]),  fmaxf(Dv[2],  Dv[3]));
            float m1 = fmaxf(fmaxf(Dv[4], Dv[5]),  fmaxf(Dv[6],  Dv[7]));
            float m2 = fmaxf(fmaxf(Dv[8], Dv[9]),  fmaxf(Dv[10], Dv[11]));
            float m3 = fmaxf(fmaxf(Dv[12],Dv[13]), fmaxf(Dv[14], Dv[15]));
            float m  = fmaxf(fmaxf(m0, m1), fmaxf(m2, m3));
            m = fmaxf(m, __shfl_xor(m, 32, 64));
            int k = (int)((__float_as_uint(m) >> 23) & 0xffu) - 126;
            offF += (float)k * LN2f;
            float sc = __uint_as_float((uint32_t)(127 - k) << 23);   // exact 2^-k
            #pragma unroll
            for (int r = 0; r < 16; ++r) Dv[r] *= sc;
        } else if (mode == 2) {
            float S = sumD();
            float inv = 1.0f / S;
            offF = 0.f;
            #pragma unroll
            for (int r = 0; r < 16; ++r) Dv[r] *= inv;
        }
        packB();
        #pragma unroll
        for (int q = 0; q < 4; ++q) {          // off-chain: Eg = exp(e_{i+1})
            Eg[4*q+0] = __expf(bu[q].x);
            Eg[4*q+1] = __expf(bu[q].y);
            Eg[4*q+2] = __expf(bu[q].z);
            Eg[4*q+3] = __expf(bu[q].w);
        }
        dswrite((u + 2) & 3, Gb);              // tile i+2 -> LDS
        gload(t0 + min(i + 4, NT - 1), Gb);    // refill Gb with tile i+4
    };

    // ---- prologue: tiles 0,1 -> LDS slots 0,1; tiles 2,3 -> G0,G1; Eg from tile 0
    gload(t0 + 0, G0);
    gload(t0 + 1, G1);
    dswrite(0, G0);
    dswrite(1, G1);
    gload(t0 + 2, G0);
    gload(t0 + 3, G1);
    {
        float4 b0[4];
        readFrag(0, b0);                       // e_{t0}
        #pragma unroll
        for (int q = 0; q < 4; ++q) {
            Eg[4*q+0] = __expf(b0[q].x);  Eg[4*q+1] = __expf(b0[q].y);
            Eg[4*q+2] = __expf(b0[q].z);  Eg[4*q+3] = __expf(b0[q].w);
        }
    }

    if (s == 0) {
        // i = 0..31; init at 0; renorm at 7,15,23
        step(0, 0, true, 0, G0);
        #pragma unroll
        for (int u = 1; u < 8; ++u) {
            const int md = (u == 7) ? 1 : 0;
            if ((u & 1) == 0) step(u, u, false, md, G0);
            else              step(u, u, false, md, G1);
        }
        #pragma unroll 1
        for (int blk = 1; blk < 4; ++blk) {
            const int base = blk * 8;
            #pragma unroll
            for (int u = 0; u < 8; ++u) {
                const int md = (u == 7 && blk < 3) ? 1 : 0;
                if ((u & 1) == 0) step(u, base + u, false, md, G0);
                else              step(u, base + u, false, md, G1);
            }
        }
    } else {
        // i = 0..47; init at 0; renorm at 7; boundary sum-normalize at 15
        // (t = s*SEGLEN - 1); renorm at 23,31,39
        step(0, 0, true, 0, G0);
        #pragma unroll
        for (int u = 1; u < 8; ++u) {
            const int md = (u == 7) ? 1 : 0;
            if ((u & 1) == 0) step(u, u, false, md, G0);
            else              step(u, u, false, md, G1);
        }
        #pragma unroll
        for (int u = 0; u < 8; ++u) {
            const int md = (u == 7) ? 2 : 0;
            if ((u & 1) == 0) step(u, 8 + u, false, md, G0);
            else              step(u, 8 + u, false, md, G1);
        }
        #pragma unroll 1
        for (int blk = 2; blk < 6; ++blk) {
            const int base = blk * 8;
            #pragma unroll
            for (int u = 0; u < 8; ++u) {
                const int md = (u == 7 && blk < 5) ? 1 : 0;
                if ((u & 1) == 0) step(u, base + u, false, md, G0);
                else              step(u, base + u, false, md, G1);
            }
        }
    }

    float Sf = sumD();
    float delta = offF + __logf(Sf);
    if (lane < 32) {
        dDelta[s * Bn + b] = delta;
    }
}

// Per-batch gold-path score + msum + last-emission + per-batch total (logZ - score).
__global__ __launch_bounds__(256) void crf_score(
    const float* __restrict__ emis, const float* __restrict__ trans,
    const int* __restrict__ tags, const int* __restrict__ mask,
    const float* __restrict__ dDelta, float* __restrict__ dVal)
{
    __shared__ float Tl[Cn * Cn];
    __shared__ float redS[4];
    __shared__ int   redM[4];
    const int b = blockIdx.x;
    const int tid = threadIdx.x;
    for (int i = tid; i < Cn * Cn; i += 256) Tl[i] = trans[i];
    __syncthreads();

    const size_t tB = (size_t)b * Ln;
    const size_t eb = (size_t)b * Ln * Cn;
    const int t0 = tid * 8;

    int tg[9], mk[9];
    {
        int4 a0 = *(const int4*)(tags + tB + t0);
        int4 a1 = *(const int4*)(tags + tB + t0 + 4);
        int4 c0 = *(const int4*)(mask + tB + t0);
        int4 c1 = *(const int4*)(mask + tB + t0 + 4);
        tg[0]=a0.x; tg[1]=a0.y; tg[2]=a0.z; tg[3]=a0.w;
        tg[4]=a1.x; tg[5]=a1.y; tg[6]=a1.z; tg[7]=a1.w;
        mk[0]=c0.x; mk[1]=c0.y; mk[2]=c0.z; mk[3]=c0.w;
        mk[4]=c1.x; mk[5]=c1.y; mk[6]=c1.z; mk[7]=c1.w;
        tg[8] = (t0 + 8 < Ln) ? tags[tB + t0 + 8] : 0;
        mk[8] = (t0 + 8 < Ln) ? mask[tB + t0 + 8] : 0;
    }

    float sc = 0.f; int ms = 0;
    #pragma unroll
    for (int u = 0; u < 8; ++u) {
        int t = t0 + u;
        ms += mk[u];
        if (t < Ln - 1) {
            sc += (float)mk[u]     * emis[eb + (size_t)t * Cn + tg[u]];
            sc += (float)mk[u + 1] * Tl[(tg[u] << 5) + tg[u + 1]];
        }
    }
    #pragma unroll
    for (int o = 32; o > 0; o >>= 1) {
        sc += __shfl_down(sc, o, 64);
        ms += __shfl_down(ms, o, 64);
    }
    if ((tid & 63) == 0) { redS[tid >> 6] = sc; redM[tid >> 6] = ms; }
    __syncthreads();

    if (tid < NSEG) {
        float lz = dDelta[(size_t)tid * Bn + b];
        #pragma unroll
        for (int o = 32; o > 0; o >>= 1) lz += __shfl_down(lz, o, 64);
        if (tid == 0) {
            float scT = redS[0] + redS[1] + redS[2] + redS[3];
            int   msT = redM[0] + redM[1] + redM[2] + redM[3];
            int last_idx = max(msT - 1, 0);
            int le_t     = max(msT, 1) - 1;
            int lt = tags[tB + last_idx];
            float le = emis[eb + (size_t)le_t * Cn + lt];
            dVal[b] = lz - (scT + le);
        }
    }
}

__global__ void crf_final(const float* __restrict__ dVal, float* __restrict__ out)
{
    __shared__ float red[8];
    int b = threadIdx.x;   // 512 threads = one per batch
    float val = dVal[b];
    #pragma unroll
    for (int o = 32; o > 0; o >>= 1) val += __shfl_down(val, o, 64);
    if ((b & 63) == 0) red[b >> 6] = val;
    __syncthreads();
    if (b == 0) {
        float t = 0.f;
        #pragma unroll
        for (int w = 0; w < 8; ++w) t += red[w];
        out[0] = t * (1.0f / (float)Bn);
    }
}

extern "C" void kernel_launch(void* const* d_in, const int* in_sizes, int n_in,
                              void* d_out, int out_size, void* d_ws, size_t ws_size,
                              hipStream_t stream)
{
    const float* emis  = (const float*)d_in[0];
    const float* trans = (const float*)d_in[1];
    const int*   tags  = (const int*)d_in[2];
    const int*   mask  = (const int*)d_in[3];
    float* wsf = (float*)d_ws;
    float* dDelta = wsf;                 // NSEG*Bn f32
    float* dVal   = wsf + NSEG * Bn;     // Bn f32
    crf_scan<<<(NGRP * NSEG) / WPB, 64 * WPB, 0, stream>>>(emis, trans, dDelta);
    crf_score<<<Bn, 256, 0, stream>>>(emis, trans, tags, mask, dDelta, dVal);
    crf_final<<<1, Bn, 0, stream>>>(dVal, (float*)d_out);
}

// Round 7
// 236.585 us; speedup vs baseline: 1.4153x; 1.0765x over previous
//
#include <hip/hip_runtime.h>
#include <stdint.h>

typedef short bf16x8 __attribute__((ext_vector_type(8)));
typedef float f32x16 __attribute__((ext_vector_type(16)));

#define LN2f  0.69314718055994530942f

constexpr int Bn = 512;
constexpr int Ln = 2048;
constexpr int Cn = 32;
constexpr int NSEG = 64;      // 1024 scan units
constexpr int SEGLEN = 32;    // Ln / NSEG
constexpr int WARM = 16;
constexpr int NGRP = 16;      // Bn / 32
constexpr int WPB  = 4;       // waves per block

// pack two f32 -> one VGPR of two bf16 (round-half-away via +0x8000, then take high halves)
__device__ __forceinline__ uint32_t pack2_bf16(float lo, float hi) {
    uint32_t a = __float_as_uint(lo) + 0x8000u;
    uint32_t b = __float_as_uint(hi) + 0x8000u;
    return __builtin_amdgcn_perm(b, a, 0x07060302u);
}

// crf_scan v7: MINIMAL-STEP ABLATION. No LDS, no DMA, no inline asm, no
// in-step gathers, exp off-chain. Six rounds showed a ~2 wave-step/us/CU wall
// invariant to occupancy, placement, memory source, request pattern, waits,
// and chain length -- every prior step still carried >=2 of {LDS round-trip,
// tag/gv gathers, in-chain exp, asm drains}. v7's step is only:
//   4x global_load_dwordx4 (per-lane direct, r0-proven) into a 4-deep NAMED
//   register ring (r6's literal-parity pattern, proven no-spill)
//   -> 2 MFMA -> 16 mul -> pack; Eg=exp(raw) runs one step off-chain.
// Numerically identical to r6 (same formula; raw path skips the LDS bounce).
// Lane (bl,h) loads floats [8q+4h .. +3] of its batch row: Dv[4q+j] multiplies
// state m = j + 8q + 4h -- matches the MFMA D-layout used since r0.
__global__ __launch_bounds__(256, 1) void crf_scan(
    const float* __restrict__ emis, const float* __restrict__ trans,
    float* __restrict__ dDelta)
{
    const int lane = threadIdx.x & 63;
    const int wid  = threadIdx.x >> 6;
    const int h    = lane >> 5;
    const int bl   = lane & 31;
    const int unit = blockIdx.x * WPB + wid;   // 0..1023
    const int g    = unit & (NGRP - 1);
    const int s    = unit >> 4;                // 0..NSEG-1
    const int b    = g * 32 + bl;

    const float* __restrict__ pb = emis + (size_t)b * Ln * Cn + 4 * h;  // per-lane base

    // Constant A fragments: A[m=bl][k'], k' = 8h + j; col(j) = 4h + (j&3) + 8*(j>>2) (+16 for A2)
    bf16x8 A1, A2;
    {
        float e1[8], e2[8];
        #pragma unroll
        for (int j = 0; j < 8; ++j) {
            int c1 = 4 * h + (j & 3) + 8 * (j >> 2);
            e1[j] = __expf(trans[bl * Cn + c1]);
            e2[j] = __expf(trans[bl * Cn + c1 + 16]);
        }
        union { uint32_t u[4]; bf16x8 v; } ua, ub;
        #pragma unroll
        for (int q = 0; q < 4; ++q) {
            ua.u[q] = pack2_bf16(e1[2*q], e1[2*q+1]);
            ub.u[q] = pack2_bf16(e2[2*q], e2[2*q+1]);
        }
        A1 = ua.v; A2 = ub.v;
    }

    const f32x16 zeroC = {0.f,0.f,0.f,0.f,0.f,0.f,0.f,0.f,0.f,0.f,0.f,0.f,0.f,0.f,0.f,0.f};

    f32x16 Dv;
    bf16x8 B1, B2;
    float  Eg[16];                       // x_i = exp(e_i), produced at step i-1
    float4 R0[4], R1[4], R2[4], R3[4];   // NAMED 4-deep raw-emission ring (64 VGPRs)
    float  offF = 0.f;

    const int t0 = (s == 0) ? 0 : s * SEGLEN - WARM;
    const int NT = (s == 0) ? SEGLEN : (SEGLEN + WARM);

    auto gload = [&](int t, float4 (&dst)[4]) {
        const float* p = pb + (size_t)t * Cn;
        dst[0] = *(const float4*)(p + 0);
        dst[1] = *(const float4*)(p + 8);
        dst[2] = *(const float4*)(p + 16);
        dst[3] = *(const float4*)(p + 24);
    };

    auto packB = [&]() {
        union { uint32_t u[4]; bf16x8 v; } p1, p2;
        #pragma unroll
        for (int q = 0; q < 4; ++q) {
            p1.u[q] = pack2_bf16(Dv[2*q],     Dv[2*q + 1]);
            p2.u[q] = pack2_bf16(Dv[8 + 2*q], Dv[8 + 2*q + 1]);
        }
        B1 = p1.v; B2 = p2.v;
    };

    auto sumD = [&]() {
        float t = 0.f;
        #pragma unroll
        for (int r = 0; r < 16; ++r) t += Dv[r];
        t += __shfl_xor(t, 32, 64);
        return t;
    };

    // step i. Rb = ring buffer holding raw e_{i+1} (loaded at step i-4 or prologue).
    // mode: 0 none, 1 pow2-renorm, 2 boundary sum-normalize.
    // Body: [MFMA x2 -> mul by Eg -> renorm -> pack]  |  off-chain: Eg=exp(Rb);
    //       reload Rb with raw tile i+5 (next read of this slot is step i+4).
    auto step = [&](int i, bool isInit, int mode, float4 (&Rb)[4]) {
        float4 bu[4];
        #pragma unroll
        for (int q = 0; q < 4; ++q) bu[q] = Rb[q];        // raw e_{i+1}
        if (isInit) {
            #pragma unroll
            for (int r = 0; r < 16; ++r) Dv[r] = Eg[r];
        } else {
            f32x16 acc = __builtin_amdgcn_mfma_f32_32x32x16_bf16(A1, B1, zeroC, 0, 0, 0);
            acc = __builtin_amdgcn_mfma_f32_32x32x16_bf16(A2, B2, acc, 0, 0, 0);
            #pragma unroll
            for (int r = 0; r < 16; ++r) Dv[r] = acc[r] * Eg[r];
        }
        if (mode == 1) {
            float m0 = fmaxf(fmaxf(Dv[0], Dv[1]),  fmaxf(Dv[2],  Dv[3]));
            float m1 = fmaxf(fmaxf(Dv[4], Dv[5]),  fmaxf(Dv[6],  Dv[7]));
            float m2 = fmaxf(fmaxf(Dv[8], Dv[9]),  fmaxf(Dv[10], Dv[11]));
            float m3 = fmaxf(fmaxf(Dv[12],Dv[13]), fmaxf(Dv[14], Dv[15]));
            float m  = fmaxf(fmaxf(m0, m1), fmaxf(m2, m3));
            m = fmaxf(m, __shfl_xor(m, 32, 64));
            int k = (int)((__float_as_uint(m) >> 23) & 0xffu) - 126;
            offF += (float)k * LN2f;
            float sc = __uint_as_float((uint32_t)(127 - k) << 23);   // exact 2^-k
            #pragma unroll
            for (int r = 0; r < 16; ++r) Dv[r] *= sc;
        } else if (mode == 2) {
            float S = sumD();
            float inv = 1.0f / S;
            offF = 0.f;
            #pragma unroll
            for (int r = 0; r < 16; ++r) Dv[r] *= inv;
        }
        packB();
        #pragma unroll
        for (int q = 0; q < 4; ++q) {          // off-chain: Eg = exp(e_{i+1})
            Eg[4*q+0] = __expf(bu[q].x);
            Eg[4*q+1] = __expf(bu[q].y);
            Eg[4*q+2] = __expf(bu[q].z);
            Eg[4*q+3] = __expf(bu[q].w);
        }
        gload(t0 + min(i + 5, NT - 1), Rb);    // refill slot with raw tile i+5
    };

    // ring slot for step i is ((i+1)&3): u=0->R1,1->R2,2->R3,3->R0,...
    auto step8 = [&](int base, bool initFirst, int modeAt7) {
        if (initFirst) step(base + 0, true,  0, R1);
        else           step(base + 0, false, 0, R1);
        step(base + 1, false, 0, R2);
        step(base + 2, false, 0, R3);
        step(base + 3, false, 0, R0);
        step(base + 4, false, 0, R1);
        step(base + 5, false, 0, R2);
        step(base + 6, false, 0, R3);
        step(base + 7, false, modeAt7, R0);
    };

    // ---- prologue: Eg from tile 0; ring <- tiles 1..4
    {
        float4 tmp[4];
        gload(t0 + 0, tmp);
        #pragma unroll
        for (int q = 0; q < 4; ++q) {
            Eg[4*q+0] = __expf(tmp[q].x);  Eg[4*q+1] = __expf(tmp[q].y);
            Eg[4*q+2] = __expf(tmp[q].z);  Eg[4*q+3] = __expf(tmp[q].w);
        }
    }
    gload(t0 + 1, R1);
    gload(t0 + 2, R2);
    gload(t0 + 3, R3);
    gload(t0 + 4, R0);

    if (s == 0) {
        // i = 0..31; init at 0; renorm at 7,15,23
        step8(0, true, 1);
        step8(8,  false, 1);
        step8(16, false, 1);
        step8(24, false, 0);
    } else {
        // i = 0..47; init at 0; renorm at 7; boundary sum-normalize at 15
        // (t = s*SEGLEN - 1); renorm at 23,31,39
        step8(0, true, 1);
        step8(8,  false, 2);
        step8(16, false, 1);
        step8(24, false, 1);
        step8(32, false, 1);
        step8(40, false, 0);
    }

    float Sf = sumD();
    float delta = offF + __logf(Sf);
    if (lane < 32) {
        dDelta[s * Bn + b] = delta;
    }
}

// Per-batch gold-path score + msum + last-emission + per-batch total (logZ - score).
__global__ __launch_bounds__(256) void crf_score(
    const float* __restrict__ emis, const float* __restrict__ trans,
    const int* __restrict__ tags, const int* __restrict__ mask,
    const float* __restrict__ dDelta, float* __restrict__ dVal)
{
    __shared__ float Tl[Cn * Cn];
    __shared__ float redS[4];
    __shared__ int   redM[4];
    const int b = blockIdx.x;
    const int tid = threadIdx.x;
    for (int i = tid; i < Cn * Cn; i += 256) Tl[i] = trans[i];
    __syncthreads();

    const size_t tB = (size_t)b * Ln;
    const size_t eb = (size_t)b * Ln * Cn;
    const int t0 = tid * 8;

    int tg[9], mk[9];
    {
        int4 a0 = *(const int4*)(tags + tB + t0);
        int4 a1 = *(const int4*)(tags + tB + t0 + 4);
        int4 c0 = *(const int4*)(mask + tB + t0);
        int4 c1 = *(const int4*)(mask + tB + t0 + 4);
        tg[0]=a0.x; tg[1]=a0.y; tg[2]=a0.z; tg[3]=a0.w;
        tg[4]=a1.x; tg[5]=a1.y; tg[6]=a1.z; tg[7]=a1.w;
        mk[0]=c0.x; mk[1]=c0.y; mk[2]=c0.z; mk[3]=c0.w;
        mk[4]=c1.x; mk[5]=c1.y; mk[6]=c1.z; mk[7]=c1.w;
        tg[8] = (t0 + 8 < Ln) ? tags[tB + t0 + 8] : 0;
        mk[8] = (t0 + 8 < Ln) ? mask[tB + t0 + 8] : 0;
    }

    float sc = 0.f; int ms = 0;
    #pragma unroll
    for (int u = 0; u < 8; ++u) {
        int t = t0 + u;
        ms += mk[u];
        if (t < Ln - 1) {
            sc += (float)mk[u]     * emis[eb + (size_t)t * Cn + tg[u]];
            sc += (float)mk[u + 1] * Tl[(tg[u] << 5) + tg[u + 1]];
        }
    }
    #pragma unroll
    for (int o = 32; o > 0; o >>= 1) {
        sc += __shfl_down(sc, o, 64);
        ms += __shfl_down(ms, o, 64);
    }
    if ((tid & 63) == 0) { redS[tid >> 6] = sc; redM[tid >> 6] = ms; }
    __syncthreads();

    if (tid < NSEG) {
        float lz = dDelta[(size_t)tid * Bn + b];
        #pragma unroll
        for (int o = 32; o > 0; o >>= 1) lz += __shfl_down(lz, o, 64);
        if (tid == 0) {
            float scT = redS[0] + redS[1] + redS[2] + redS[3];
            int   msT = redM[0] + redM[1] + redM[2] + redM[3];
            int last_idx = max(msT - 1, 0);
            int le_t     = max(msT, 1) - 1;
            int lt = tags[tB + last_idx];
            float le = emis[eb + (size_t)le_t * Cn + lt];
            dVal[b] = lz - (scT + le);
        }
    }
}

__global__ void crf_final(const float* __restrict__ dVal, float* __restrict__ out)
{
    __shared__ float red[8];
    int b = threadIdx.x;   // 512 threads = one per batch
    float val = dVal[b];
    #pragma unroll
    for (int o = 32; o > 0; o >>= 1) val += __shfl_down(val, o, 64);
    if ((b & 63) == 0) red[b >> 6] = val;
    __syncthreads();
    if (b == 0) {
        float t = 0.f;
        #pragma unroll
        for (int w = 0; w < 8; ++w) t += red[w];
        out[0] = t * (1.0f / (float)Bn);
    }
}

extern "C" void kernel_launch(void* const* d_in, const int* in_sizes, int n_in,
                              void* d_out, int out_size, void* d_ws, size_t ws_size,
                              hipStream_t stream)
{
    const float* emis  = (const float*)d_in[0];
    const float* trans = (const float*)d_in[1];
    const int*   tags  = (const int*)d_in[2];
    const int*   mask  = (const int*)d_in[3];
    float* wsf = (float*)d_ws;
    float* dDelta = wsf;                 // NSEG*Bn f32
    float* dVal   = wsf + NSEG * Bn;     // Bn f32
    crf_scan<<<(NGRP * NSEG) / WPB, 64 * WPB, 0, stream>>>(emis, trans, dDelta);
    crf_score<<<Bn, 256, 0, stream>>>(emis, trans, tags, mask, dDelta, dVal);
    crf_final<<<1, Bn, 0, stream>>>(dVal, (float*)d_out);
}

// Round 8
// 234.156 us; speedup vs baseline: 1.4300x; 1.0104x over previous
//
#include <hip/hip_runtime.h>
#include <stdint.h>

typedef short bf16x8 __attribute__((ext_vector_type(8)));
typedef float f32x16 __attribute__((ext_vector_type(16)));

#define LN2f  0.69314718055994530942f

constexpr int Bn = 512;
constexpr int Ln = 2048;
constexpr int Cn = 32;
constexpr int NSEG = 128;     // 2048 scan units -> 512 blocks -> 2 blocks/CU (8 waves/CU)
constexpr int SEGLEN = 16;    // Ln / NSEG
constexpr int WARM = 16;
constexpr int NGRP = 16;      // Bn / 32
constexpr int WPB  = 4;       // waves per block

// pack two f32 -> one VGPR of two bf16 (round-half-away via +0x8000, then take high halves)
__device__ __forceinline__ uint32_t pack2_bf16(float lo, float hi) {
    uint32_t a = __float_as_uint(lo) + 0x8000u;
    uint32_t b = __float_as_uint(hi) + 0x8000u;
    return __builtin_amdgcn_perm(b, a, 0x07060302u);
}

// crf_scan v8 = v7's minimal step at 8 waves/CU (the one untried axis).
// v7 post-mortem: scan ~71us (hidden under 80us harness fills). Minimal step
// (no LDS/DMA/gathers, exp off-chain) still shows ~3500 cyc per wave-step vs
// ~100 cyc dependency chain and ~180 cyc issue -- a per-wave stall that
// survived every memory/structure redesign. All rounds ran exactly 4 waves/CU.
// If the stall is per-wave (overlappable), 8 waves/CU doubles throughput.
// NSEG 64->128: SEGLEN=16, WARM=16 (same warm depth => same accuracy),
// 2048 units, 512 blocks, __launch_bounds__(256,2) = 2 blocks/CU.
__global__ __launch_bounds__(256, 2) void crf_scan(
    const float* __restrict__ emis, const float* __restrict__ trans,
    float* __restrict__ dDelta)
{
    const int lane = threadIdx.x & 63;
    const int wid  = threadIdx.x >> 6;
    const int h    = lane >> 5;
    const int bl   = lane & 31;
    const int unit = blockIdx.x * WPB + wid;   // 0..2047
    const int g    = unit & (NGRP - 1);
    const int s    = unit >> 4;                // 0..NSEG-1
    const int b    = g * 32 + bl;

    const float* __restrict__ pb = emis + (size_t)b * Ln * Cn + 4 * h;  // per-lane base

    // Constant A fragments: A[m=bl][k'], k' = 8h + j; col(j) = 4h + (j&3) + 8*(j>>2) (+16 for A2)
    bf16x8 A1, A2;
    {
        float e1[8], e2[8];
        #pragma unroll
        for (int j = 0; j < 8; ++j) {
            int c1 = 4 * h + (j & 3) + 8 * (j >> 2);
            e1[j] = __expf(trans[bl * Cn + c1]);
            e2[j] = __expf(trans[bl * Cn + c1 + 16]);
        }
        union { uint32_t u[4]; bf16x8 v; } ua, ub;
        #pragma unroll
        for (int q = 0; q < 4; ++q) {
            ua.u[q] = pack2_bf16(e1[2*q], e1[2*q+1]);
            ub.u[q] = pack2_bf16(e2[2*q], e2[2*q+1]);
        }
        A1 = ua.v; A2 = ub.v;
    }

    const f32x16 zeroC = {0.f,0.f,0.f,0.f,0.f,0.f,0.f,0.f,0.f,0.f,0.f,0.f,0.f,0.f,0.f,0.f};

    f32x16 Dv;
    bf16x8 B1, B2;
    float  Eg[16];                       // x_i = exp(e_i), produced at step i-1
    float4 R0[4], R1[4], R2[4], R3[4];   // NAMED 4-deep raw-emission ring (64 VGPRs)
    float  offF = 0.f;

    const int t0 = (s == 0) ? 0 : s * SEGLEN - WARM;
    const int NT = (s == 0) ? SEGLEN : (SEGLEN + WARM);

    auto gload = [&](int t, float4 (&dst)[4]) {
        const float* p = pb + (size_t)t * Cn;
        dst[0] = *(const float4*)(p + 0);
        dst[1] = *(const float4*)(p + 8);
        dst[2] = *(const float4*)(p + 16);
        dst[3] = *(const float4*)(p + 24);
    };

    auto packB = [&]() {
        union { uint32_t u[4]; bf16x8 v; } p1, p2;
        #pragma unroll
        for (int q = 0; q < 4; ++q) {
            p1.u[q] = pack2_bf16(Dv[2*q],     Dv[2*q + 1]);
            p2.u[q] = pack2_bf16(Dv[8 + 2*q], Dv[8 + 2*q + 1]);
        }
        B1 = p1.v; B2 = p2.v;
    };

    auto sumD = [&]() {
        float t = 0.f;
        #pragma unroll
        for (int r = 0; r < 16; ++r) t += Dv[r];
        t += __shfl_xor(t, 32, 64);
        return t;
    };

    // step i. Rb = ring buffer holding raw e_{i+1} (loaded at step i-4 or prologue).
    // mode: 0 none, 1 pow2-renorm, 2 boundary sum-normalize.
    auto step = [&](int i, bool isInit, int mode, float4 (&Rb)[4]) {
        float4 bu[4];
        #pragma unroll
        for (int q = 0; q < 4; ++q) bu[q] = Rb[q];        // raw e_{i+1}
        if (isInit) {
            #pragma unroll
            for (int r = 0; r < 16; ++r) Dv[r] = Eg[r];
        } else {
            f32x16 acc = __builtin_amdgcn_mfma_f32_32x32x16_bf16(A1, B1, zeroC, 0, 0, 0);
            acc = __builtin_amdgcn_mfma_f32_32x32x16_bf16(A2, B2, acc, 0, 0, 0);
            #pragma unroll
            for (int r = 0; r < 16; ++r) Dv[r] = acc[r] * Eg[r];
        }
        if (mode == 1) {
            float m0 = fmaxf(fmaxf(Dv[0], Dv[1]),  fmaxf(Dv[2],  Dv[3]));
            float m1 = fmaxf(fmaxf(Dv[4], Dv[5]),  fmaxf(Dv[6],  Dv[7]));
            float m2 = fmaxf(fmaxf(Dv[8], Dv[9]),  fmaxf(Dv[10], Dv[11]));
            float m3 = fmaxf(fmaxf(Dv[12],Dv[13]), fmaxf(Dv[14], Dv[15]));
            float m  = fmaxf(fmaxf(m0, m1), fmaxf(m2, m3));
            m = fmaxf(m, __shfl_xor(m, 32, 64));
            int k = (int)((__float_as_uint(m) >> 23) & 0xffu) - 126;
            offF += (float)k * LN2f;
            float sc = __uint_as_float((uint32_t)(127 - k) << 23);   // exact 2^-k
            #pragma unroll
            for (int r = 0; r < 16; ++r) Dv[r] *= sc;
        } else if (mode == 2) {
            float S = sumD();
            float inv = 1.0f / S;
            offF = 0.f;
            #pragma unroll
            for (int r = 0; r < 16; ++r) Dv[r] *= inv;
        }
        packB();
        #pragma unroll
        for (int q = 0; q < 4; ++q) {          // off-chain: Eg = exp(e_{i+1})
            Eg[4*q+0] = __expf(bu[q].x);
            Eg[4*q+1] = __expf(bu[q].y);
            Eg[4*q+2] = __expf(bu[q].z);
            Eg[4*q+3] = __expf(bu[q].w);
        }
        gload(t0 + min(i + 5, NT - 1), Rb);    // refill slot with raw tile i+5
    };

    // ring slot for step i is ((i+1)&3): i%8=0->R1,1->R2,2->R3,3->R0,...
    auto step8 = [&](int base, bool initFirst, int modeAt7) {
        if (initFirst) step(base + 0, true,  0, R1);
        else           step(base + 0, false, 0, R1);
        step(base + 1, false, 0, R2);
        step(base + 2, false, 0, R3);
        step(base + 3, false, 0, R0);
        step(base + 4, false, 0, R1);
        step(base + 5, false, 0, R2);
        step(base + 6, false, 0, R3);
        step(base + 7, false, modeAt7, R0);
    };

    // ---- prologue: Eg from tile 0; ring <- tiles 1..4
    {
        float4 tmp[4];
        gload(t0 + 0, tmp);
        #pragma unroll
        for (int q = 0; q < 4; ++q) {
            Eg[4*q+0] = __expf(tmp[q].x);  Eg[4*q+1] = __expf(tmp[q].y);
            Eg[4*q+2] = __expf(tmp[q].z);  Eg[4*q+3] = __expf(tmp[q].w);
        }
    }
    gload(t0 + 1, R1);
    gload(t0 + 2, R2);
    gload(t0 + 3, R3);
    gload(t0 + 4, R0);

    if (s == 0) {
        // i = 0..15; init at 0; renorm at 7
        step8(0, true, 1);
        step8(8, false, 0);
    } else {
        // i = 0..31; init at 0; renorm at 7; boundary sum-normalize at 15
        // (t = s*SEGLEN - 1); renorm at 23
        step8(0,  true,  1);
        step8(8,  false, 2);
        step8(16, false, 1);
        step8(24, false, 0);
    }

    float Sf = sumD();
    float delta = offF + __logf(Sf);
    if (lane < 32) {
        dDelta[s * Bn + b] = delta;
    }
}

// Per-batch gold-path score + msum + last-emission + per-batch total (logZ - score).
__global__ __launch_bounds__(256) void crf_score(
    const float* __restrict__ emis, const float* __restrict__ trans,
    const int* __restrict__ tags, const int* __restrict__ mask,
    const float* __restrict__ dDelta, float* __restrict__ dVal)
{
    __shared__ float Tl[Cn * Cn];
    __shared__ float redS[4];
    __shared__ int   redM[4];
    __shared__ float redL[4];
    const int b = blockIdx.x;
    const int tid = threadIdx.x;
    for (int i = tid; i < Cn * Cn; i += 256) Tl[i] = trans[i];
    __syncthreads();

    const size_t tB = (size_t)b * Ln;
    const size_t eb = (size_t)b * Ln * Cn;
    const int t0 = tid * 8;

    int tg[9], mk[9];
    {
        int4 a0 = *(const int4*)(tags + tB + t0);
        int4 a1 = *(const int4*)(tags + tB + t0 + 4);
        int4 c0 = *(const int4*)(mask + tB + t0);
        int4 c1 = *(const int4*)(mask + tB + t0 + 4);
        tg[0]=a0.x; tg[1]=a0.y; tg[2]=a0.z; tg[3]=a0.w;
        tg[4]=a1.x; tg[5]=a1.y; tg[6]=a1.z; tg[7]=a1.w;
        mk[0]=c0.x; mk[1]=c0.y; mk[2]=c0.z; mk[3]=c0.w;
        mk[4]=c1.x; mk[5]=c1.y; mk[6]=c1.z; mk[7]=c1.w;
        tg[8] = (t0 + 8 < Ln) ? tags[tB + t0 + 8] : 0;
        mk[8] = (t0 + 8 < Ln) ? mask[tB + t0 + 8] : 0;
    }

    float sc = 0.f; int ms = 0;
    #pragma unroll
    for (int u = 0; u < 8; ++u) {
        int t = t0 + u;
        ms += mk[u];
        if (t < Ln - 1) {
            sc += (float)mk[u]     * emis[eb + (size_t)t * Cn + tg[u]];
            sc += (float)mk[u + 1] * Tl[(tg[u] << 5) + tg[u + 1]];
        }
    }
    #pragma unroll
    for (int o = 32; o > 0; o >>= 1) {
        sc += __shfl_down(sc, o, 64);
        ms += __shfl_down(ms, o, 64);
    }
    if ((tid & 63) == 0) { redS[tid >> 6] = sc; redM[tid >> 6] = ms; }

    // segment-delta reduction: NSEG=128 partials, threads 0..127 load, all 4
    // waves shuffle-reduce (upper waves contribute 0), LDS-combine.
    float lz = (tid < NSEG) ? dDelta[(size_t)tid * Bn + b] : 0.f;
    #pragma unroll
    for (int o = 32; o > 0; o >>= 1) lz += __shfl_down(lz, o, 64);
    if ((tid & 63) == 0) redL[tid >> 6] = lz;
    __syncthreads();

    if (tid == 0) {
        float lzT = redL[0] + redL[1] + redL[2] + redL[3];
        float scT = redS[0] + redS[1] + redS[2] + redS[3];
        int   msT = redM[0] + redM[1] + redM[2] + redM[3];
        int last_idx = max(msT - 1, 0);
        int le_t     = max(msT, 1) - 1;
        int lt = tags[tB + last_idx];
        float le = emis[eb + (size_t)le_t * Cn + lt];
        dVal[b] = lzT - (scT + le);
    }
}

__global__ void crf_final(const float* __restrict__ dVal, float* __restrict__ out)
{
    __shared__ float red[8];
    int b = threadIdx.x;   // 512 threads = one per batch
    float val = dVal[b];
    #pragma unroll
    for (int o = 32; o > 0; o >>= 1) val += __shfl_down(val, o, 64);
    if ((b & 63) == 0) red[b >> 6] = val;
    __syncthreads();
    if (b == 0) {
        float t = 0.f;
        #pragma unroll
        for (int w = 0; w < 8; ++w) t += red[w];
        out[0] = t * (1.0f / (float)Bn);
    }
}

extern "C" void kernel_launch(void* const* d_in, const int* in_sizes, int n_in,
                              void* d_out, int out_size, void* d_ws, size_t ws_size,
                              hipStream_t stream)
{
    const float* emis  = (const float*)d_in[0];
    const float* trans = (const float*)d_in[1];
    const int*   tags  = (const int*)d_in[2];
    const int*   mask  = (const int*)d_in[3];
    float* wsf = (float*)d_ws;
    float* dDelta = wsf;                 // NSEG*Bn f32
    float* dVal   = wsf + NSEG * Bn;     // Bn f32
    crf_scan<<<(NGRP * NSEG) / WPB, 64 * WPB, 0, stream>>>(emis, trans, dDelta);
    crf_score<<<Bn, 256, 0, stream>>>(emis, trans, tags, mask, dDelta, dVal);
    crf_final<<<1, Bn, 0, stream>>>(dVal, (float*)d_out);
}